// Round 10
// baseline (632.882 us; speedup 1.0000x reference)
//
#include <hip/hip_runtime.h>
#include <hip/hip_cooperative_groups.h>
#include <cstddef>

#define TT 2048
#define BB 64
#define DD 256
#define LN_EPS 1e-5f
#define WEPS 1e-4f

namespace cg = cooperative_groups;

typedef __attribute__((ext_vector_type(8))) short short8;
typedef __attribute__((ext_vector_type(4))) float f32x4;
typedef __attribute__((ext_vector_type(8))) _Float16 f16x8;
typedef __attribute__((ext_vector_type(4))) _Float16 f16x4;

__device__ __forceinline__ unsigned short f2h(float f) {
  _Float16 h = (_Float16)f;
  return *(unsigned short*)&h;
}
__device__ __forceinline__ float h2f(unsigned short u) {
  _Float16 h = *(_Float16*)&u;
  return (float)h;
}
// async global->LDS, 16B/lane; dest wave-uniform base (+lane*16 by HW)
__device__ __forceinline__ void gload16(unsigned short* lds, const unsigned short* g) {
  __builtin_amdgcn_global_load_lds(
      (const __attribute__((address_space(1))) void*)g,
      (__attribute__((address_space(3))) void*)lds, 16, 0, 0);
}

// ---- K1: fused LN stats + column partial sums (single x pass) ----
__global__ __launch_bounds__(256) void prepass_kernel(const float* __restrict__ x,
    float* __restrict__ stats, float* __restrict__ part) {
  int c = blockIdx.x;
  int b = blockIdx.y;
  int tid = threadIdx.x;
  int wave = tid >> 6, lane = tid & 63;
  int rowbase = b * TT + c * 128 + wave * 32;
  const float* xb = x + (size_t)rowbase * DD + lane * 4;
  float a0 = 0.f, a1 = 0.f, a2 = 0.f, a3 = 0.f;
  for (int i = 0; i < 32; ++i) {
    float4 v = *(const float4*)&xb[(size_t)i * DD];
    float s  = v.x + v.y + v.z + v.w;
    float sq = v.x*v.x + v.y*v.y + v.z*v.z + v.w*v.w;
    #pragma unroll
    for (int off = 32; off; off >>= 1) { s += __shfl_xor(s, off); sq += __shfl_xor(sq, off); }
    float mean = s * (1.f/DD);
    float var  = fmaxf(sq * (1.f/DD) - mean*mean, 0.f);
    float rstd = rsqrtf(var + LN_EPS);
    if (lane == 0) {
      stats[2*(rowbase+i)]   = mean;
      stats[2*(rowbase+i)+1] = rstd;
    }
    a0 += (v.x - mean) * rstd;
    a1 += (v.y - mean) * rstd;
    a2 += (v.z - mean) * rstd;
    a3 += (v.w - mean) * rstd;
  }
  int pidx = c * 4 + wave;
  *(float4*)&part[((size_t)pidx*BB + b)*DD + lane*4] = make_float4(a0, a1, a2, a3);
}

__global__ __launch_bounds__(256) void mu_finalize_kernel(const float* __restrict__ part,
                                                          const float* __restrict__ gamma,
                                                          const float* __restrict__ beta,
                                                          float* __restrict__ mu) {
  int b = blockIdx.x;
  int d = threadIdx.x;
  float s = 0.f;
  #pragma unroll 8
  for (int c = 0; c < 64; ++c) s += part[((size_t)c*BB + b)*DD + d];
  mu[b*DD + d] = gamma[d] * s * (1.f/TT) + beta[d];
}

// ---- K3: cov via fp16 MFMA: C = Gram(Xc^T)/(T-1) + eps I -> fp16 plane ----
__global__ __launch_bounds__(256) void cov_mfma(const float* __restrict__ x,
    const float* __restrict__ stats, const float* __restrict__ gamma,
    const float* __restrict__ beta, const float* __restrict__ mu,
    unsigned short* __restrict__ Ch) {
  int flat = blockIdx.y * gridDim.x + blockIdx.x;  // [0,640); XCD-bijective remap
  int kx = flat & 7, j = flat >> 3;
  int b = (kx << 3) + j / 10;
  int tile = j - (j / 10) * 10;
  int p = 0, t = tile;
  while (t >= 4 - p) { t -= (4 - p); ++p; }
  int q = p + t;
  int i0 = p * 64, j0 = q * 64;
  bool diag = (p == q);

  __shared__ unsigned short sm[8448];
  unsigned short* sA = sm;
  unsigned short* sB = sm + 4096;
  __shared__ float sGi[64], sBi[64], sGj[64], sBj[64];

  int tid = threadIdx.x;
  const float* mub = mu + (size_t)b*DD;
  if (tid < 64) {
    sGi[tid] = gamma[i0+tid]; sBi[tid] = beta[i0+tid] - mub[i0+tid];
    sGj[tid] = gamma[j0+tid]; sBj[tid] = beta[j0+tid] - mub[j0+tid];
  }
  __syncthreads();

  int wave = tid >> 6, lane = tid & 63;
  int lr = lane & 15, lg = lane >> 4;
  int tg4 = tid >> 4;
  int dg  = tid & 15;
  int d0 = dg * 4;
  const float* xb  = x + (size_t)b*TT*DD;
  const float* stb = stats + (size_t)b*TT*2;

  float4 gi4 = *(const float4*)&sGi[d0];
  float4 bi4 = *(const float4*)&sBi[d0];
  float4 gj4 = *(const float4*)&sGj[d0];
  float4 bj4 = *(const float4*)&sBj[d0];

  int ch16 = tg4 >> 1, half = tg4 & 1;
  int widx[4];
  #pragma unroll
  for (int jj = 0; jj < 4; ++jj) {
    int dl = d0 + jj;
    int swz = (ch16 ^ (dl & 7) ^ ((dl >> 3) & 7)) & 7;
    widx[jj] = dl*64 + swz*8 + half*4;
  }

  f32x4 acc[4] = {};

  for (int k0 = 0; k0 < TT; k0 += 64) {
    int trow = k0 + tg4 * 4;
    float4 s01 = *(const float4*)&stb[2*trow];
    float4 s23 = *(const float4*)&stb[2*trow + 4];
    float mm[4] = {s01.x, s01.z, s23.x, s23.z};
    float rr[4] = {s01.y, s01.w, s23.y, s23.w};
    {
      _Float16 va[4][4];
      #pragma unroll
      for (int i = 0; i < 4; ++i) {
        float4 v = *(const float4*)&xb[(size_t)(trow+i)*DD + i0 + d0];
        va[i][0] = (_Float16)(((v.x - mm[i]) * rr[i]) * gi4.x + bi4.x);
        va[i][1] = (_Float16)(((v.y - mm[i]) * rr[i]) * gi4.y + bi4.y);
        va[i][2] = (_Float16)(((v.z - mm[i]) * rr[i]) * gi4.z + bi4.z);
        va[i][3] = (_Float16)(((v.w - mm[i]) * rr[i]) * gi4.w + bi4.w);
      }
      #pragma unroll
      for (int jj = 0; jj < 4; ++jj) {
        f16x4 w = {va[0][jj], va[1][jj], va[2][jj], va[3][jj]};
        *(f16x4*)&sA[widx[jj]] = w;
      }
    }
    if (!diag) {
      _Float16 vb[4][4];
      #pragma unroll
      for (int i = 0; i < 4; ++i) {
        float4 v = *(const float4*)&xb[(size_t)(trow+i)*DD + j0 + d0];
        vb[i][0] = (_Float16)(((v.x - mm[i]) * rr[i]) * gj4.x + bj4.x);
        vb[i][1] = (_Float16)(((v.y - mm[i]) * rr[i]) * gj4.y + bj4.y);
        vb[i][2] = (_Float16)(((v.z - mm[i]) * rr[i]) * gj4.z + bj4.z);
        vb[i][3] = (_Float16)(((v.w - mm[i]) * rr[i]) * gj4.w + bj4.w);
      }
      #pragma unroll
      for (int jj = 0; jj < 4; ++jj) {
        f16x4 w = {vb[0][jj], vb[1][jj], vb[2][jj], vb[3][jj]};
        *(f16x4*)&sB[widx[jj]] = w;
      }
    }
    __syncthreads();
    const unsigned short* pB = diag ? sA : sB;
    #pragma unroll
    for (int ks = 0; ks < 2; ++ks) {
      int rowA = wave*16 + lr;
      int cc = ks*4 + lg;
      int aoff = rowA*64 + (((cc ^ (rowA&7) ^ ((rowA>>3)&7)) & 7) << 3);
      f16x8 av = *(const f16x8*)&sA[aoff];
      #pragma unroll
      for (int n = 0; n < 4; ++n) {
        int rowB = n*16 + lr;
        int boff = rowB*64 + (((cc ^ (rowB&7) ^ ((rowB>>3)&7)) & 7) << 3);
        f16x8 bv = *(const f16x8*)&pB[boff];
        acc[n] = __builtin_amdgcn_mfma_f32_16x16x32_f16(av, bv, acc[n], 0, 0, 0);
      }
    }
    __syncthreads();
  }

  float* sC = (float*)sm;
  #pragma unroll
  for (int n = 0; n < 4; ++n)
    #pragma unroll
    for (int r = 0; r < 4; ++r)
      sC[(wave*16 + lg*4 + r)*65 + n*16 + lr] = acc[n][r];
  __syncthreads();
  unsigned short* Chb = Ch + (size_t)b*DD*DD;
  const float invTm1 = 1.f / (float)(TT - 1);
  int row = tid >> 2, cb = (tid & 3) * 16;
  int gi = i0 + row;
  unsigned short hv[16];
  #pragma unroll
  for (int e = 0; e < 16; ++e) {
    float v = sC[row*65 + cb + e] * invTm1;
    int gj = j0 + cb + e;
    if (gi == gj) v += WEPS;
    hv[e] = f2h(v);
    if (!diag) Chb[(size_t)gj*DD + gi] = hv[e];
  }
  size_t go = (size_t)gi*DD + j0 + cb;
  *(short8*)&Chb[go]     = *(short8*)&hv[0];
  *(short8*)&Chb[go + 8] = *(short8*)&hv[8];
}

// ---- 128x128-tile fp16 MFMA GEMM body, global_load_lds staging (shared by chain) ----
__device__ __forceinline__ void bgemm_tile2(
    const unsigned short* __restrict__ A, const unsigned short* __restrict__ B,
    unsigned short* __restrict__ C,
    float alpha, float diagBeta, int tilex, int b, unsigned short* sm) {
  unsigned short* sA = sm;          // 128x64 fp16 = 16 KB
  unsigned short* sB = sm + 8192;

  const int tid = threadIdx.x;
  const int i0g = (tilex >> 1) * 128, j0g = (tilex & 1) * 128;
  const size_t mb = (size_t)b * DD * DD;
  const int wave = tid >> 6, lane = tid & 63;
  const int wr = wave >> 2, wc = wave & 3;
  const int lr = lane & 15, lg = lane >> 4;

  f32x4 acc[8] = {};

  for (int k0 = 0; k0 < DD; k0 += 64) {
    #pragma unroll
    for (int p2 = 0; p2 < 2; ++p2) {
      int slot = tid + p2 * 512;
      int row = slot >> 3, c = slot & 7;
      int srcc = (c ^ (row & 7)) << 3;             // pre-swizzled source chunk
      size_t ga = mb + (size_t)(i0g + row) * DD + k0 + srcc;
      size_t gb = mb + (size_t)(j0g + row) * DD + k0 + srcc;  // B symmetric
      int base = (wave * 64 + p2 * 512) * 8;       // wave-uniform dest
      gload16(&sA[base], A + ga);
      gload16(&sB[base], B + gb);
    }
    __syncthreads();
    #pragma unroll
    for (int ks = 0; ks < 2; ++ks) {
      int cc = ks * 4 + lg;
      f16x8 bv[2];
      #pragma unroll
      for (int n = 0; n < 2; ++n) {
        int rowB = wc * 32 + n * 16 + lr;
        int boff = rowB * 64 + ((cc ^ (rowB & 7)) * 8);
        bv[n] = *(const f16x8*)&sB[boff];
      }
      #pragma unroll
      for (int m = 0; m < 4; ++m) {
        int rowA = wr * 64 + m * 16 + lr;
        int aoff = rowA * 64 + ((cc ^ (rowA & 7)) * 8);
        f16x8 av = *(const f16x8*)&sA[aoff];
        #pragma unroll
        for (int n = 0; n < 2; ++n)
          acc[m*2+n] = __builtin_amdgcn_mfma_f32_16x16x32_f16(av, bv[n], acc[m*2+n], 0, 0, 0);
      }
    }
    __syncthreads();
  }

  #pragma unroll
  for (int m = 0; m < 4; ++m) {
    #pragma unroll
    for (int n = 0; n < 2; ++n) {
      int col = j0g + wc * 32 + n * 16 + lr;
      int row0 = i0g + wr * 64 + m * 16 + lg * 4;
      #pragma unroll
      for (int r = 0; r < 4; ++r) {
        float vv = alpha * acc[m*2+n][r];
        int row = row0 + r;
        if (row == col) vv += diagBeta;
        C[mb + (size_t)row * DD + col] = f2h(vv);
      }
    }
  }
}

// ---- Cooperative chain: power iteration + ew(M1,Z1) + 12 GEMM-tiles in 9 phases ----
// 256 blocks x 512 threads, 1 block/CU (129 KB LDS). Buffer flow identical to r9.
__global__ void __launch_bounds__(512, 1) ns_chain(
    unsigned short* H0, unsigned short* H1, unsigned short* H2,
    unsigned short* H3, unsigned short* H4, float* sbuf) {
  cg::grid_group grid = cg::this_grid();
  __shared__ unsigned short sm[65536];   // 128 KB (power C-stage; GEMMs use first 32 KB)
  __shared__ float vv[DD];
  __shared__ float red[4];
  const int blk = blockIdx.x;
  const int tid = threadIdx.x;

  // --- Phase P: power iteration, blocks 0..63 (one batch each) ---
  if (blk < BB) {
    const unsigned short* Cb = H0 + (size_t)blk*DD*DD;
    #pragma unroll
    for (int i = 0; i < 16; ++i) {
      int chunkid = i*512 + tid;           // 0..8191
      int r = chunkid >> 5, ch = chunkid & 31;
      short8 qv = *(const short8*)&Cb[(size_t)chunkid*8];
      *(short8*)&sm[r*256 + ((ch ^ (r & 7)) << 3)] = qv;
    }
    if (tid < DD) {
      unsigned u = (unsigned)tid * 2654435761u;
      vv[tid] = 0.5f + (float)((u >> 9) & 1023) * (1.f/1024.f);
    }
    __syncthreads();
    float lam = 1.f;
    for (int it = 0; it < 10; ++it) {
      float w = 0.f;
      if (tid < DD) {
        #pragma unroll
        for (int ch = 0; ch < 32; ++ch) {
          short8 hq = *(const short8*)&sm[tid*256 + ((ch ^ (tid & 7)) << 3)];
          const float* vp = &vv[ch*8];
          #pragma unroll
          for (int e = 0; e < 8; ++e) w += h2f((unsigned short)hq[e]) * vp[e];
        }
      }
      float ssq = w * w;
      #pragma unroll
      for (int off = 32; off; off >>= 1) ssq += __shfl_xor(ssq, off);
      if (tid < DD && (tid & 63) == 0) red[tid >> 6] = ssq;
      __syncthreads();
      float nrm = sqrtf(red[0] + red[1] + red[2] + red[3]);
      lam = nrm;
      if (tid < DD) vv[tid] = w / nrm;
      __syncthreads();
    }
    if (tid == 0) sbuf[blk] = lam * 1.12f;
  }
  grid.sync();

  // --- Phase EW: M1 = 3I - C/s (H2); Z1 = 1.5I - 0.5 C/s (H1) ---
  {
    #pragma unroll
    for (int i = 0; i < 4; ++i) {
      int chunk = blk*2048 + i*512 + tid;      // 0..524287 short8-chunks
      int b = chunk >> 13;
      int within = chunk & 8191;
      int row = within >> 5, cb = (within & 31) * 8;
      float inv = 1.f / sbuf[b];
      size_t off = (size_t)chunk * 8;
      short8 cv = *(const short8*)&H0[off];
      unsigned short mo[8], zo[8];
      #pragma unroll
      for (int e = 0; e < 8; ++e) {
        float c = h2f((unsigned short)cv[e]) * inv;
        float dg = (row == cb + e) ? 1.f : 0.f;
        mo[e] = f2h(3.f*dg - c);
        zo[e] = f2h(1.5f*dg - 0.5f*c);
      }
      *(short8*)&H2[off] = *(short8*)&mo[0];
      *(short8*)&H1[off] = *(short8*)&zo[0];
    }
  }
  grid.sync();

  // tile mapping (XCD-bijective): 256 units
  int kx = blk & 7, j = blk >> 3;
  int gb = (kx << 3) + (j >> 2);
  int gtile = j & 3;

  // P1: Y1 = (0.5/s) C*M1 -> H3
  bgemm_tile2(H0, H2, H3, 0.5f / sbuf[gb], 0.f, gtile, gb, sm);
  grid.sync();
  // P2: M2 = 3I - Z1*Y1 -> H2
  bgemm_tile2(H1, H3, H2, -1.f, 3.f, gtile, gb, sm);
  grid.sync();
  // P3: Y2 = 0.5 Y1*M2 -> H0 ; Z2 = 0.5 M2*Z1 -> H4
  bgemm_tile2(H3, H2, H0, 0.5f, 0.f, gtile, gb, sm);
  bgemm_tile2(H2, H1, H4, 0.5f, 0.f, gtile, gb, sm);
  grid.sync();
  // P4: M3 = 3I - Z2*Y2 -> H2
  bgemm_tile2(H4, H0, H2, -1.f, 3.f, gtile, gb, sm);
  grid.sync();
  // P5: Y3 = 0.5 Y2*M3 -> H3 ; Z3 = 0.5 M3*Z2 -> H1
  bgemm_tile2(H0, H2, H3, 0.5f, 0.f, gtile, gb, sm);
  bgemm_tile2(H2, H4, H1, 0.5f, 0.f, gtile, gb, sm);
  grid.sync();
  // P6: M4 = 3I - Z3*Y3 -> H2
  bgemm_tile2(H1, H3, H2, -1.f, 3.f, gtile, gb, sm);
  grid.sync();
  // P7: Y4 = 0.5 Y3*M4 -> H0 ; Z4 = 0.5 M4*Z3 -> H4
  bgemm_tile2(H3, H2, H0, 0.5f, 0.f, gtile, gb, sm);
  bgemm_tile2(H2, H1, H4, 0.5f, 0.f, gtile, gb, sm);
  grid.sync();
  // P8: M5 = 3I - Z4*Y4 -> H2
  bgemm_tile2(H4, H0, H2, -1.f, 3.f, gtile, gb, sm);
  grid.sync();
  // P9: Z5 = 0.5 M5*Z4 -> H1
  bgemm_tile2(H2, H4, H1, 0.5f, 0.f, gtile, gb, sm);
}

// ---- K6: out = Xc @ (Z / sqrt(s)); 128x128 tile, 512 thr ----
__global__ __launch_bounds__(512) void out_mfma2(const float* __restrict__ x,
    const float* __restrict__ stats, const float* __restrict__ gamma,
    const float* __restrict__ beta, const float* __restrict__ mu,
    const unsigned short* __restrict__ Z, const float* __restrict__ sbuf,
    float* __restrict__ out) {
  int flat = blockIdx.y * gridDim.x + blockIdx.x;  // [0,2048)
  int kx = flat & 7, j = flat >> 3;                // j in [0,256)
  int b = (kx << 3) + (j >> 5);
  int tile = j & 31;                               // 16 t-tiles x 2 f-tiles
  int t0 = (tile >> 1) * 128, f0 = (tile & 1) * 128;
  __shared__ unsigned short sm[16384];             // sA 16KB + sB 16KB
  unsigned short* sA = sm;
  unsigned short* sB = sm + 8192;
  __shared__ float sG[256], sBs[256];

  int tid = threadIdx.x;
  if (tid < 256) {
    sG[tid] = gamma[tid];
    sBs[tid] = beta[tid] - mu[(size_t)b*DD + tid];
  }
  __syncthreads();

  const int wave = tid >> 6, lane = tid & 63;
  const int wr = wave >> 2, wc = wave & 3;
  const int lr = lane & 15, lg = lane >> 4;
  const float* xb  = x + (size_t)b*TT*DD;
  const float* stb = stats + (size_t)b*TT*2;
  const unsigned short* Zb = Z + (size_t)b*DD*DD;

  f32x4 acc[8] = {};

  for (int k0 = 0; k0 < DD; k0 += 64) {
    #pragma unroll
    for (int p2 = 0; p2 < 2; ++p2) {
      int slot = tid + p2 * 512;
      int row = slot >> 3, c0 = slot & 7;
      int srcc = (c0 ^ (row & 7)) << 3;
      size_t gz = (size_t)(f0 + row) * DD + k0 + srcc;
      int base = (wave * 64 + p2 * 512) * 8;
      gload16(&sB[base], Zb + gz);
      int trow = t0 + row;
      float mean = stb[2*trow], rstd = stb[2*trow+1];
      const float* xr = xb + (size_t)trow*DD + k0 + c0*8;
      _Float16 h8[8];
      #pragma unroll
      for (int qq = 0; qq < 2; ++qq) {
        float4 v = *(const float4*)&xr[qq*4];
        float vvv[4] = {v.x, v.y, v.z, v.w};
        #pragma unroll
        for (int e2 = 0; e2 < 4; ++e2) {
          int d = k0 + c0*8 + qq*4 + e2;
          h8[qq*4+e2] = (_Float16)((vvv[e2] - mean) * rstd * sG[d] + sBs[d]);
        }
      }
      int ld = row * 64 + ((c0 ^ (row & 7)) * 8);
      *(f16x8*)&sA[ld] = *(f16x8*)&h8[0];
    }
    __syncthreads();
    #pragma unroll
    for (int ks = 0; ks < 2; ++ks) {
      int cc = ks * 4 + lg;
      f16x8 bv[2];
      #pragma unroll
      for (int n = 0; n < 2; ++n) {
        int rowB = wc * 32 + n * 16 + lr;
        int boff = rowB * 64 + ((cc ^ (rowB & 7)) * 8);
        bv[n] = *(const f16x8*)&sB[boff];
      }
      #pragma unroll
      for (int m = 0; m < 4; ++m) {
        int rowA = wr * 64 + m * 16 + lr;
        int aoff = rowA * 64 + ((cc ^ (rowA & 7)) * 8);
        f16x8 av = *(const f16x8*)&sA[aoff];
        #pragma unroll
        for (int n = 0; n < 2; ++n)
          acc[m*2+n] = __builtin_amdgcn_mfma_f32_16x16x32_f16(av, bv[n], acc[m*2+n], 0, 0, 0);
      }
    }
    __syncthreads();
  }

  float rs = rsqrtf(sbuf[b]);
  float* ob = out + (size_t)b*TT*DD;
  #pragma unroll
  for (int m = 0; m < 4; ++m) {
    #pragma unroll
    for (int n = 0; n < 2; ++n) {
      int col = f0 + wc * 32 + n * 16 + lr;
      int row0 = t0 + wr * 64 + m * 16 + lg * 4;
      #pragma unroll
      for (int r = 0; r < 4; ++r)
        ob[(size_t)(row0 + r)*DD + col] = acc[m*2+n][r] * rs;
    }
  }
}

extern "C" void kernel_launch(void* const* d_in, const int* in_sizes, int n_in,
                              void* d_out, int out_size, void* d_ws, size_t ws_size,
                              hipStream_t stream) {
  const float* x     = (const float*)d_in[0];
  const float* gamma = (const float*)d_in[1];
  const float* beta  = (const float*)d_in[2];
  float* out = (float*)d_out;

  float* wsf   = (float*)d_ws;
  float* stats = wsf;                      // 262144 floats (1 MB)
  float* mu    = wsf + 262144;             // 16384
  float* sbuf  = wsf + 278528;             // 64
  unsigned short* nsb = (unsigned short*)(wsf + 278784);
  const size_t MATU = (size_t)BB * DD * DD;      // 4194304 ushorts (8 MB) per plane
  unsigned short* H[5];
  for (int k = 0; k < 5; ++k) H[k] = nsb + (size_t)k * MATU;
  // part (4 MB) aliased onto H1 (first written inside ns_chain, after mu_finalize)
  float* part = (float*)H[1];

  prepass_kernel<<<dim3(16, BB), 256, 0, stream>>>(x, stats, part);
  mu_finalize_kernel<<<BB, 256, 0, stream>>>(part, gamma, beta, mu);
  cov_mfma<<<dim3(10, BB), 256, 0, stream>>>(x, stats, gamma, beta, mu, H[0]);

  unsigned short *h0 = H[0], *h1 = H[1], *h2 = H[2], *h3 = H[3], *h4 = H[4];
  float* sb = sbuf;
  void* kargs[] = {&h0, &h1, &h2, &h3, &h4, &sb};
  hipLaunchCooperativeKernel((void*)ns_chain, dim3(256), dim3(512), kargs, 0, stream);

  out_mfma2<<<dim3(32, BB), 512, 0, stream>>>(x, stats, gamma, beta, mu, H[1], sbuf, out);
}

// Round 11
// 218.459 us; speedup vs baseline: 2.8970x; 2.8970x over previous
//
#include <hip/hip_runtime.h>
#include <cstddef>

#define TT 2048
#define BB 64
#define DD 256
#define LN_EPS 1e-5f
#define WEPS 1e-4f

typedef __attribute__((ext_vector_type(8))) short short8;
typedef __attribute__((ext_vector_type(4))) float f32x4;
typedef __attribute__((ext_vector_type(8))) _Float16 f16x8;
typedef __attribute__((ext_vector_type(4))) _Float16 f16x4;

__device__ __forceinline__ unsigned short f2h(float f) {
  _Float16 h = (_Float16)f;
  return *(unsigned short*)&h;
}
__device__ __forceinline__ float h2f(unsigned short u) {
  _Float16 h = *(_Float16*)&u;
  return (float)h;
}
// async global->LDS, 16B/lane; dest wave-uniform base (+lane*16 by HW)
__device__ __forceinline__ void gload16(unsigned short* lds, const unsigned short* g) {
  __builtin_amdgcn_global_load_lds(
      (const __attribute__((address_space(1))) void*)g,
      (__attribute__((address_space(3))) void*)lds, 16, 0, 0);
}

// ---- K1: fused LN stats + column partial sums (single x pass) ----
__global__ __launch_bounds__(256) void prepass_kernel(const float* __restrict__ x,
    float* __restrict__ stats, float* __restrict__ part) {
  int c = blockIdx.x;
  int b = blockIdx.y;
  int tid = threadIdx.x;
  int wave = tid >> 6, lane = tid & 63;
  int rowbase = b * TT + c * 128 + wave * 32;
  const float* xb = x + (size_t)rowbase * DD + lane * 4;
  float a0 = 0.f, a1 = 0.f, a2 = 0.f, a3 = 0.f;
  for (int i = 0; i < 32; ++i) {
    float4 v = *(const float4*)&xb[(size_t)i * DD];
    float s  = v.x + v.y + v.z + v.w;
    float sq = v.x*v.x + v.y*v.y + v.z*v.z + v.w*v.w;
    #pragma unroll
    for (int off = 32; off; off >>= 1) { s += __shfl_xor(s, off); sq += __shfl_xor(sq, off); }
    float mean = s * (1.f/DD);
    float var  = fmaxf(sq * (1.f/DD) - mean*mean, 0.f);
    float rstd = rsqrtf(var + LN_EPS);
    if (lane == 0) {
      stats[2*(rowbase+i)]   = mean;
      stats[2*(rowbase+i)+1] = rstd;
    }
    a0 += (v.x - mean) * rstd;
    a1 += (v.y - mean) * rstd;
    a2 += (v.z - mean) * rstd;
    a3 += (v.w - mean) * rstd;
  }
  int pidx = c * 4 + wave;
  *(float4*)&part[((size_t)pidx*BB + b)*DD + lane*4] = make_float4(a0, a1, a2, a3);
}

__global__ __launch_bounds__(256) void mu_finalize_kernel(const float* __restrict__ part,
                                                          const float* __restrict__ gamma,
                                                          const float* __restrict__ beta,
                                                          float* __restrict__ mu) {
  int b = blockIdx.x;
  int d = threadIdx.x;
  float s = 0.f;
  #pragma unroll 8
  for (int c = 0; c < 64; ++c) s += part[((size_t)c*BB + b)*DD + d];
  mu[b*DD + d] = gamma[d] * s * (1.f/TT) + beta[d];
}

// ---- K3: cov via fp16 MFMA: C = Gram(Xc^T)/(T-1) + eps I -> fp16 plane ----
__global__ __launch_bounds__(256) void cov_mfma(const float* __restrict__ x,
    const float* __restrict__ stats, const float* __restrict__ gamma,
    const float* __restrict__ beta, const float* __restrict__ mu,
    unsigned short* __restrict__ Ch) {
  int flat = blockIdx.y * gridDim.x + blockIdx.x;  // [0,640); XCD-bijective remap
  int kx = flat & 7, j = flat >> 3;
  int b = (kx << 3) + j / 10;
  int tile = j - (j / 10) * 10;
  int p = 0, t = tile;
  while (t >= 4 - p) { t -= (4 - p); ++p; }
  int q = p + t;
  int i0 = p * 64, j0 = q * 64;
  bool diag = (p == q);

  __shared__ unsigned short sm[8448];
  unsigned short* sA = sm;
  unsigned short* sB = sm + 4096;
  __shared__ float sGi[64], sBi[64], sGj[64], sBj[64];

  int tid = threadIdx.x;
  const float* mub = mu + (size_t)b*DD;
  if (tid < 64) {
    sGi[tid] = gamma[i0+tid]; sBi[tid] = beta[i0+tid] - mub[i0+tid];
    sGj[tid] = gamma[j0+tid]; sBj[tid] = beta[j0+tid] - mub[j0+tid];
  }
  __syncthreads();

  int wave = tid >> 6, lane = tid & 63;
  int lr = lane & 15, lg = lane >> 4;
  int tg4 = tid >> 4;
  int dg  = tid & 15;
  int d0 = dg * 4;
  const float* xb  = x + (size_t)b*TT*DD;
  const float* stb = stats + (size_t)b*TT*2;

  float4 gi4 = *(const float4*)&sGi[d0];
  float4 bi4 = *(const float4*)&sBi[d0];
  float4 gj4 = *(const float4*)&sGj[d0];
  float4 bj4 = *(const float4*)&sBj[d0];

  int ch16 = tg4 >> 1, half = tg4 & 1;
  int widx[4];
  #pragma unroll
  for (int jj = 0; jj < 4; ++jj) {
    int dl = d0 + jj;
    int swz = (ch16 ^ (dl & 7) ^ ((dl >> 3) & 7)) & 7;
    widx[jj] = dl*64 + swz*8 + half*4;
  }

  f32x4 acc[4] = {};

  for (int k0 = 0; k0 < TT; k0 += 64) {
    int trow = k0 + tg4 * 4;
    float4 s01 = *(const float4*)&stb[2*trow];
    float4 s23 = *(const float4*)&stb[2*trow + 4];
    float mm[4] = {s01.x, s01.z, s23.x, s23.z};
    float rr[4] = {s01.y, s01.w, s23.y, s23.w};
    {
      _Float16 va[4][4];
      #pragma unroll
      for (int i = 0; i < 4; ++i) {
        float4 v = *(const float4*)&xb[(size_t)(trow+i)*DD + i0 + d0];
        va[i][0] = (_Float16)(((v.x - mm[i]) * rr[i]) * gi4.x + bi4.x);
        va[i][1] = (_Float16)(((v.y - mm[i]) * rr[i]) * gi4.y + bi4.y);
        va[i][2] = (_Float16)(((v.z - mm[i]) * rr[i]) * gi4.z + bi4.z);
        va[i][3] = (_Float16)(((v.w - mm[i]) * rr[i]) * gi4.w + bi4.w);
      }
      #pragma unroll
      for (int jj = 0; jj < 4; ++jj) {
        f16x4 w = {va[0][jj], va[1][jj], va[2][jj], va[3][jj]};
        *(f16x4*)&sA[widx[jj]] = w;
      }
    }
    if (!diag) {
      _Float16 vb[4][4];
      #pragma unroll
      for (int i = 0; i < 4; ++i) {
        float4 v = *(const float4*)&xb[(size_t)(trow+i)*DD + j0 + d0];
        vb[i][0] = (_Float16)(((v.x - mm[i]) * rr[i]) * gj4.x + bj4.x);
        vb[i][1] = (_Float16)(((v.y - mm[i]) * rr[i]) * gj4.y + bj4.y);
        vb[i][2] = (_Float16)(((v.z - mm[i]) * rr[i]) * gj4.z + bj4.z);
        vb[i][3] = (_Float16)(((v.w - mm[i]) * rr[i]) * gj4.w + bj4.w);
      }
      #pragma unroll
      for (int jj = 0; jj < 4; ++jj) {
        f16x4 w = {vb[0][jj], vb[1][jj], vb[2][jj], vb[3][jj]};
        *(f16x4*)&sB[widx[jj]] = w;
      }
    }
    __syncthreads();
    const unsigned short* pB = diag ? sA : sB;
    #pragma unroll
    for (int ks = 0; ks < 2; ++ks) {
      int rowA = wave*16 + lr;
      int cc = ks*4 + lg;
      int aoff = rowA*64 + (((cc ^ (rowA&7) ^ ((rowA>>3)&7)) & 7) << 3);
      f16x8 av = *(const f16x8*)&sA[aoff];
      #pragma unroll
      for (int n = 0; n < 4; ++n) {
        int rowB = n*16 + lr;
        int boff = rowB*64 + (((cc ^ (rowB&7) ^ ((rowB>>3)&7)) & 7) << 3);
        f16x8 bv = *(const f16x8*)&pB[boff];
        acc[n] = __builtin_amdgcn_mfma_f32_16x16x32_f16(av, bv, acc[n], 0, 0, 0);
      }
    }
    __syncthreads();
  }

  float* sC = (float*)sm;
  #pragma unroll
  for (int n = 0; n < 4; ++n)
    #pragma unroll
    for (int r = 0; r < 4; ++r)
      sC[(wave*16 + lg*4 + r)*65 + n*16 + lr] = acc[n][r];
  __syncthreads();
  unsigned short* Chb = Ch + (size_t)b*DD*DD;
  const float invTm1 = 1.f / (float)(TT - 1);
  int row = tid >> 2, cb = (tid & 3) * 16;
  int gi = i0 + row;
  unsigned short hv[16];
  #pragma unroll
  for (int e = 0; e < 16; ++e) {
    float v = sC[row*65 + cb + e] * invTm1;
    int gj = j0 + cb + e;
    if (gi == gj) v += WEPS;
    hv[e] = f2h(v);
    if (!diag) Chb[(size_t)gj*DD + gi] = hv[e];
  }
  size_t go = (size_t)gi*DD + j0 + cb;
  *(short8*)&Chb[go]     = *(short8*)&hv[0];
  *(short8*)&Chb[go + 8] = *(short8*)&hv[8];
}

// ---- K3b: power iteration in LDS (fp16 C); s = 1.05 * ||C v|| ----
__global__ __launch_bounds__(256) void power_kernel(
    const unsigned short* __restrict__ Ch, float* __restrict__ sbuf) {
  int b = blockIdx.x, tid = threadIdx.x;
  __shared__ unsigned short sC[DD*DD];   // 128 KB
  __shared__ float v[DD];
  __shared__ float red[4];
  const unsigned short* Cb = Ch + (size_t)b*DD*DD;
  #pragma unroll
  for (int i = 0; i < 32; ++i) {
    int chunkid = i*256 + tid;
    int r = chunkid >> 5, ch = chunkid & 31;
    short8 qv = *(const short8*)&Cb[(size_t)chunkid*8];
    *(short8*)&sC[r*256 + ((ch ^ (r & 7)) << 3)] = qv;
  }
  unsigned u = (unsigned)tid * 2654435761u;
  v[tid] = 0.5f + (float)((u >> 9) & 1023) * (1.f/1024.f);
  __syncthreads();
  float lam = 1.f;
  for (int it = 0; it < 10; ++it) {
    float w = 0.f;
    #pragma unroll
    for (int ch = 0; ch < 32; ++ch) {
      short8 hq = *(const short8*)&sC[tid*256 + ((ch ^ (tid & 7)) << 3)];
      const float* vp = &v[ch*8];
      #pragma unroll
      for (int e = 0; e < 8; ++e) w += h2f((unsigned short)hq[e]) * vp[e];
    }
    float ssq = w * w;
    #pragma unroll
    for (int off = 32; off; off >>= 1) ssq += __shfl_xor(ssq, off);
    if ((tid & 63) == 0) red[tid >> 6] = ssq;
    __syncthreads();
    float nrm = sqrtf(red[0] + red[1] + red[2] + red[3]);
    lam = nrm;
    v[tid] = w / nrm;
    __syncthreads();
  }
  if (tid == 0) sbuf[b] = lam * 1.05f;
}

// ---- 128x128-tile fp16 MFMA GEMM body, global_load_lds staging ----
__device__ __forceinline__ void bgemm_tile2(
    const unsigned short* __restrict__ A, const unsigned short* __restrict__ B,
    unsigned short* __restrict__ C,
    float alpha, float diagBeta, int tilex, int b, unsigned short* sm) {
  unsigned short* sA = sm;          // 128x64 fp16 = 16 KB
  unsigned short* sB = sm + 8192;

  const int tid = threadIdx.x;
  const int i0g = (tilex >> 1) * 128, j0g = (tilex & 1) * 128;
  const size_t mb = (size_t)b * DD * DD;
  const int wave = tid >> 6, lane = tid & 63;
  const int wr = wave >> 2, wc = wave & 3;
  const int lr = lane & 15, lg = lane >> 4;

  f32x4 acc[8] = {};

  for (int k0 = 0; k0 < DD; k0 += 64) {
    #pragma unroll
    for (int p2 = 0; p2 < 2; ++p2) {
      int slot = tid + p2 * 512;
      int row = slot >> 3, c = slot & 7;
      int srcc = (c ^ (row & 7)) << 3;             // pre-swizzled source chunk
      size_t ga = mb + (size_t)(i0g + row) * DD + k0 + srcc;
      size_t gb = mb + (size_t)(j0g + row) * DD + k0 + srcc;  // B symmetric
      int base = (wave * 64 + p2 * 512) * 8;       // wave-uniform dest
      gload16(&sA[base], A + ga);
      gload16(&sB[base], B + gb);
    }
    __syncthreads();
    #pragma unroll
    for (int ks = 0; ks < 2; ++ks) {
      int cc = ks * 4 + lg;
      f16x8 bv[2];
      #pragma unroll
      for (int n = 0; n < 2; ++n) {
        int rowB = wc * 32 + n * 16 + lr;
        int boff = rowB * 64 + ((cc ^ (rowB & 7)) * 8);
        bv[n] = *(const f16x8*)&sB[boff];
      }
      #pragma unroll
      for (int m = 0; m < 4; ++m) {
        int rowA = wr * 64 + m * 16 + lr;
        int aoff = rowA * 64 + ((cc ^ (rowA & 7)) * 8);
        f16x8 av = *(const f16x8*)&sA[aoff];
        #pragma unroll
        for (int n = 0; n < 2; ++n)
          acc[m*2+n] = __builtin_amdgcn_mfma_f32_16x16x32_f16(av, bv[n], acc[m*2+n], 0, 0, 0);
      }
    }
    __syncthreads();
  }

  #pragma unroll
  for (int m = 0; m < 4; ++m) {
    #pragma unroll
    for (int n = 0; n < 2; ++n) {
      int col = j0g + wc * 32 + n * 16 + lr;
      int row0 = i0g + wr * 64 + m * 16 + lg * 4;
      #pragma unroll
      for (int r = 0; r < 4; ++r) {
        float vv = alpha * acc[m*2+n][r];
        int row = row0 + r;
        if (row == col) vv += diagBeta;
        C[mb + (size_t)row * DD + col] = f2h(vv);
      }
    }
  }
}

__global__ __launch_bounds__(512) void bgemm_mfma2(
    const unsigned short* __restrict__ A, const unsigned short* __restrict__ B,
    unsigned short* __restrict__ C, float alpha, float diagBeta) {
  __shared__ unsigned short sm[16384];
  int flat = blockIdx.y * gridDim.x + blockIdx.x;
  int kx = flat & 7, j = flat >> 3;
  int b = (kx << 3) + (j >> 2);
  int tile = j & 3;
  bgemm_tile2(A, B, C, alpha, diagBeta, tile, b, sm);
}

__global__ __launch_bounds__(512) void bgemm_dual2(
    const unsigned short* __restrict__ A0, const unsigned short* __restrict__ B0,
    unsigned short* __restrict__ C0,
    const unsigned short* __restrict__ A1, const unsigned short* __restrict__ B1,
    unsigned short* __restrict__ C1) {
  __shared__ unsigned short sm[16384];
  int flat = blockIdx.y * gridDim.x + blockIdx.x;
  int kx = flat & 7, j = flat >> 3;
  int b = (kx << 3) + (j >> 3);
  int t8 = j & 7;
  int half = t8 >> 2, tile = t8 & 3;
  if (half == 0)
    bgemm_tile2(A0, B0, C0, 0.5f, 0.f, tile, b, sm);
  else
    bgemm_tile2(A1, B1, C1, 0.5f, 0.f, tile, b, sm);
}

// ---- P0: fused first NS iteration from C alone:
//   Y1 = (1.5/s) C - (0.5/s^2) C*C   (GEMM + linear-in-C epilogue)
//   Z1 = 1.5 I - (0.5/s) C           (elementwise, same C tile)
__global__ __launch_bounds__(512) void bgemm_p0(
    const unsigned short* __restrict__ C, unsigned short* __restrict__ Y1,
    unsigned short* __restrict__ Z1, const float* __restrict__ sbuf) {
  __shared__ unsigned short sm[16384];
  unsigned short* sA = sm;
  unsigned short* sB = sm + 8192;
  int flat = blockIdx.y * gridDim.x + blockIdx.x;
  int kx = flat & 7, j = flat >> 3;
  int b = (kx << 3) + (j >> 2);
  int tilex = j & 3;

  const int tid = threadIdx.x;
  const int i0g = (tilex >> 1) * 128, j0g = (tilex & 1) * 128;
  const size_t mb = (size_t)b * DD * DD;
  const int wave = tid >> 6, lane = tid & 63;
  const int wr = wave >> 2, wc = wave & 3;
  const int lr = lane & 15, lg = lane >> 4;

  f32x4 acc[8] = {};

  for (int k0 = 0; k0 < DD; k0 += 64) {
    #pragma unroll
    for (int p2 = 0; p2 < 2; ++p2) {
      int slot = tid + p2 * 512;
      int row = slot >> 3, c = slot & 7;
      int srcc = (c ^ (row & 7)) << 3;
      size_t ga = mb + (size_t)(i0g + row) * DD + k0 + srcc;
      size_t gb = mb + (size_t)(j0g + row) * DD + k0 + srcc;  // C symmetric
      int base = (wave * 64 + p2 * 512) * 8;
      gload16(&sA[base], C + ga);
      gload16(&sB[base], C + gb);
    }
    __syncthreads();
    #pragma unroll
    for (int ks = 0; ks < 2; ++ks) {
      int cc = ks * 4 + lg;
      f16x8 bv[2];
      #pragma unroll
      for (int n = 0; n < 2; ++n) {
        int rowB = wc * 32 + n * 16 + lr;
        int boff = rowB * 64 + ((cc ^ (rowB & 7)) * 8);
        bv[n] = *(const f16x8*)&sB[boff];
      }
      #pragma unroll
      for (int m = 0; m < 4; ++m) {
        int rowA = wr * 64 + m * 16 + lr;
        int aoff = rowA * 64 + ((cc ^ (rowA & 7)) * 8);
        f16x8 av = *(const f16x8*)&sA[aoff];
        #pragma unroll
        for (int n = 0; n < 2; ++n)
          acc[m*2+n] = __builtin_amdgcn_mfma_f32_16x16x32_f16(av, bv[n], acc[m*2+n], 0, 0, 0);
      }
    }
    __syncthreads();
  }

  float invs = 1.f / sbuf[b];
  float a2 = -0.5f * invs * invs;
  float a1c = 1.5f * invs;
  float z1c = -0.5f * invs;
  #pragma unroll
  for (int m = 0; m < 4; ++m) {
    #pragma unroll
    for (int n = 0; n < 2; ++n) {
      int col = j0g + wc * 32 + n * 16 + lr;
      int row0 = i0g + wr * 64 + m * 16 + lg * 4;
      #pragma unroll
      for (int r = 0; r < 4; ++r) {
        int row = row0 + r;
        float cv = h2f(C[mb + (size_t)row * DD + col]);
        float yv = a2 * acc[m*2+n][r] + a1c * cv;
        float zv = z1c * cv + ((row == col) ? 1.5f : 0.f);
        Y1[mb + (size_t)row * DD + col] = f2h(yv);
        Z1[mb + (size_t)row * DD + col] = f2h(zv);
      }
    }
  }
}

// ---- K6: out = Xc @ (Z / sqrt(s)); 128x128 tile, 512 thr ----
__global__ __launch_bounds__(512) void out_mfma2(const float* __restrict__ x,
    const float* __restrict__ stats, const float* __restrict__ gamma,
    const float* __restrict__ beta, const float* __restrict__ mu,
    const unsigned short* __restrict__ Z, const float* __restrict__ sbuf,
    float* __restrict__ out) {
  int flat = blockIdx.y * gridDim.x + blockIdx.x;  // [0,2048)
  int kx = flat & 7, j = flat >> 3;                // j in [0,256)
  int b = (kx << 3) + (j >> 5);
  int tile = j & 31;                               // 16 t-tiles x 2 f-tiles
  int t0 = (tile >> 1) * 128, f0 = (tile & 1) * 128;
  __shared__ unsigned short sm[16384];             // sA 16KB + sB 16KB
  unsigned short* sA = sm;
  unsigned short* sB = sm + 8192;
  __shared__ float sG[256], sBs[256];

  int tid = threadIdx.x;
  if (tid < 256) {
    sG[tid] = gamma[tid];
    sBs[tid] = beta[tid] - mu[(size_t)b*DD + tid];
  }
  __syncthreads();

  const int wave = tid >> 6, lane = tid & 63;
  const int wr = wave >> 2, wc = wave & 3;
  const int lr = lane & 15, lg = lane >> 4;
  const float* xb  = x + (size_t)b*TT*DD;
  const float* stb = stats + (size_t)b*TT*2;
  const unsigned short* Zb = Z + (size_t)b*DD*DD;

  f32x4 acc[8] = {};

  for (int k0 = 0; k0 < DD; k0 += 64) {
    #pragma unroll
    for (int p2 = 0; p2 < 2; ++p2) {
      int slot = tid + p2 * 512;
      int row = slot >> 3, c0 = slot & 7;
      int srcc = (c0 ^ (row & 7)) << 3;
      size_t gz = (size_t)(f0 + row) * DD + k0 + srcc;
      int base = (wave * 64 + p2 * 512) * 8;
      gload16(&sB[base], Zb + gz);
      int trow = t0 + row;
      float mean = stb[2*trow], rstd = stb[2*trow+1];
      const float* xr = xb + (size_t)trow*DD + k0 + c0*8;
      _Float16 h8[8];
      #pragma unroll
      for (int qq = 0; qq < 2; ++qq) {
        float4 v = *(const float4*)&xr[qq*4];
        float vvv[4] = {v.x, v.y, v.z, v.w};
        #pragma unroll
        for (int e2 = 0; e2 < 4; ++e2) {
          int d = k0 + c0*8 + qq*4 + e2;
          h8[qq*4+e2] = (_Float16)((vvv[e2] - mean) * rstd * sG[d] + sBs[d]);
        }
      }
      int ld = row * 64 + ((c0 ^ (row & 7)) * 8);
      *(f16x8*)&sA[ld] = *(f16x8*)&h8[0];
    }
    __syncthreads();
    #pragma unroll
    for (int ks = 0; ks < 2; ++ks) {
      int cc = ks * 4 + lg;
      f16x8 bv[2];
      #pragma unroll
      for (int n = 0; n < 2; ++n) {
        int rowB = wc * 32 + n * 16 + lr;
        int boff = rowB * 64 + ((cc ^ (rowB & 7)) * 8);
        bv[n] = *(const f16x8*)&sB[boff];
      }
      #pragma unroll
      for (int m = 0; m < 4; ++m) {
        int rowA = wr * 64 + m * 16 + lr;
        int aoff = rowA * 64 + ((cc ^ (rowA & 7)) * 8);
        f16x8 av = *(const f16x8*)&sA[aoff];
        #pragma unroll
        for (int n = 0; n < 2; ++n)
          acc[m*2+n] = __builtin_amdgcn_mfma_f32_16x16x32_f16(av, bv[n], acc[m*2+n], 0, 0, 0);
      }
    }
    __syncthreads();
  }

  float rs = rsqrtf(sbuf[b]);
  float* ob = out + (size_t)b*TT*DD;
  #pragma unroll
  for (int m = 0; m < 4; ++m) {
    #pragma unroll
    for (int n = 0; n < 2; ++n) {
      int col = f0 + wc * 32 + n * 16 + lr;
      int row0 = t0 + wr * 64 + m * 16 + lg * 4;
      #pragma unroll
      for (int r = 0; r < 4; ++r)
        ob[(size_t)(row0 + r)*DD + col] = acc[m*2+n][r] * rs;
    }
  }
}

extern "C" void kernel_launch(void* const* d_in, const int* in_sizes, int n_in,
                              void* d_out, int out_size, void* d_ws, size_t ws_size,
                              hipStream_t stream) {
  const float* x     = (const float*)d_in[0];
  const float* gamma = (const float*)d_in[1];
  const float* beta  = (const float*)d_in[2];
  float* out = (float*)d_out;

  float* wsf   = (float*)d_ws;
  float* stats = wsf;                      // 262144 floats (1 MB)
  float* mu    = wsf + 262144;             // 16384
  float* sbuf  = wsf + 278528;             // 64
  unsigned short* nsb = (unsigned short*)(wsf + 278784);
  const size_t MATU = (size_t)BB * DD * DD;      // 4194304 ushorts (8 MB) per plane
  unsigned short* H[5];
  for (int k = 0; k < 5; ++k) H[k] = nsb + (size_t)k * MATU;
  // part (4 MB) aliased onto H1 (first written in P0, after mu_finalize reads it)
  float* part = (float*)H[1];

  prepass_kernel<<<dim3(16, BB), 256, 0, stream>>>(x, stats, part);
  mu_finalize_kernel<<<BB, 256, 0, stream>>>(part, gamma, beta, mu);
  cov_mfma<<<dim3(10, BB), 256, 0, stream>>>(x, stats, gamma, beta, mu, H[0]);
  power_kernel<<<BB, 256, 0, stream>>>(H[0], sbuf);

  // P0 (it1, fused): Y1 -> H3 ; Z1 -> H1       [C = H0]
  bgemm_p0<<<dim3(4, BB), 512, 0, stream>>>(H[0], H[3], H[1], sbuf);
  // it2: M2 = 3I - Z1*Y1 -> H2 ; Y2 = 0.5 Y1*M2 -> H0 ; Z2 = 0.5 M2*Z1 -> H4
  bgemm_mfma2<<<dim3(4, BB), 512, 0, stream>>>(H[1], H[3], H[2], -1.f, 3.f);
  bgemm_dual2<<<dim3(8, BB), 512, 0, stream>>>(H[3], H[2], H[0], H[2], H[1], H[4]);
  // it3: M3 -> H2 ; Y3 = 0.5 Y2*M3 -> H3 ; Z3 = 0.5 M3*Z2 -> H1
  bgemm_mfma2<<<dim3(4, BB), 512, 0, stream>>>(H[4], H[0], H[2], -1.f, 3.f);
  bgemm_dual2<<<dim3(8, BB), 512, 0, stream>>>(H[0], H[2], H[3], H[2], H[4], H[1]);
  // it4 (Z-only): M4 -> H2 ; Z4 = 0.5 M4*Z3 -> H4
  bgemm_mfma2<<<dim3(4, BB), 512, 0, stream>>>(H[1], H[3], H[2], -1.f, 3.f);
  bgemm_mfma2<<<dim3(4, BB), 512, 0, stream>>>(H[2], H[1], H[4], 0.5f, 0.f);

  out_mfma2<<<dim3(32, BB), 512, 0, stream>>>(x, stats, gamma, beta, mu, H[4], sbuf, out);
}